// Round 1
// baseline (239.687 us; speedup 1.0000x reference)
//
#include <hip/hip_runtime.h>
#include <cmath>

#define NBINS 257   // spectrum bins per frame
#define NCH   40    // mel channels
#define MORD  16    // PLP order
#define NR    17    // autocorr lags (MORD+1)
#define NY    42    // y length after edge duplication
#define CHUNK 16    // frames staged in LDS at once
#define FPB   64    // frames per block

__global__ __launch_bounds__(256) void plp_kernel(const float* __restrict__ x,
                                                  float* __restrict__ out,
                                                  int nframes)
{
    __shared__ float xs[CHUNK][257];     // bins 1..256 of each staged frame (bin b at [b-1])
    __shared__ float ys[CHUNK][NY + 1];  // padded to 43 floats (odd stride -> no LDS conflicts)
    __shared__ float rs[FPB][NR];        // autocorr per frame (stride 17, odd)
    __shared__ float ttab[256];          // t_b = mel(bin b)*41/mel_max, b=1..255
    __shared__ int   sstart[NCH + 2];    // first bin with t_b > c, c=0..41
    __shared__ float eql_s[NCH];
    __shared__ float lift_s[NR];
    __shared__ float ct[NR][NY + 1];     // folded hfft cosine table, padded stride 43

    const int tid = threadIdx.x;
    const double PI = 3.14159265358979323846;

    // ---- per-block constant setup (double precision, ~200 ops/thread, redundant per block) ----
    const double MELMAX = 1127.0 * log1p(8000.0 / 700.0);
    const double U = MELMAX / 41.0;   // constant mel spacing: diff[ch] == U for all ch
    if (tid < 255) {
        int b = tid + 1;
        double mel = 1127.0 * log1p((31.25 * (double)b) / 700.0);
        ttab[b] = (float)(mel / U);
    }
    if (tid < NCH + 2) {
        // start[c] = min{ b : mel_b > c*U } = floor(700/31.25 * expm1(c*U/1127)) + 1
        double thr = 22.4 * expm1(((double)tid * U) / 1127.0);
        int s = (int)floor(thr) + 1;
        s = s < 1 ? 1 : (s > 256 ? 256 : s);
        sstart[tid] = s;
    }
    if (tid < NCH) {
        double cf = 700.0 * expm1(((double)(tid + 1) * U) / 1127.0);
        double f2 = cf * cf;
        double e  = f2 / (f2 + 160000.0);
        e = e * e * (f2 + 1440000.0) / (f2 + 9610000.0);
        eql_s[tid] = (float)e;
    }
    if (tid < NR) {
        lift_s[tid] = (float)(1.0 + 11.0 * sin(PI * (double)tid / 22.0));
    }
    for (int idx = tid; idx < NR * NY; idx += 256) {
        int l = idx / NY, j = idx % NY;
        // r[l] = ( y0 + 2*sum_{j=1..40} y_j cos(pi j l / 41) + y41*cos(pi l) ) / 82
        double s = (j == 0 || j == NY - 1) ? 1.0 : 2.0;
        ct[l][j] = (float)(s * cos(PI * (double)(j * l) / 41.0) / 82.0);
    }
    __syncthreads();

    const long long frame0 = (long long)blockIdx.x * FPB;

    // ---- phase 1: cooperative r[0..16] for 64 frames, in 4 chunks of 16 ----
    for (int chk = 0; chk < FPB / CHUNK; ++chk) {
        const long long cf0 = frame0 + (long long)chk * CHUNK;

        // coalesced load: thread t loads bin (t+1) of each frame
        #pragma unroll
        for (int i = 0; i < CHUNK; ++i) {
            long long fr = cf0 + i;
            if (fr > (long long)nframes - 1) fr = (long long)nframes - 1;
            xs[i][tid] = x[fr * NBINS + 1 + tid];
        }
        __syncthreads();

        // sparse filterbank + cube-root compression -> ys
        for (int task = tid; task < CHUNK * NCH; task += 256) {
            int f = task / NCH, c = task % NCH;
            int s0 = sstart[c], s1 = sstart[c + 1], s2 = sstart[c + 2];
            float acc = 0.f;
            // bins with implied ch==c contribute (1-w) = t_b - c to fb[c]
            for (int b = s0; b < s1; ++b) acc = fmaf(ttab[b] - (float)c, xs[f][b - 1], acc);
            // bins with implied ch==c+1 contribute w = (c+2) - t_b to fb[c]
            for (int b = s1; b < s2; ++b) acc = fmaf((float)(c + 2) - ttab[b], xs[f][b - 1], acc);
            float v  = fmaxf(acc, 1e-5f) * eql_s[c];
            float yv = powf(v, 0.33f);
            ys[f][c + 1] = yv;
            if (c == 0)       ys[f][0]      = yv;  // edge duplicate
            if (c == NCH - 1) ys[f][NY - 1] = yv;  // edge duplicate
        }
        __syncthreads();

        // hfft-as-cosine-transform -> rs
        for (int task = tid; task < CHUNK * NR; task += 256) {
            int f = task / NR, l = task % NR;
            float acc = 0.f;
            #pragma unroll
            for (int j = 0; j < NY; ++j) acc = fmaf(ct[l][j], ys[f][j], acc);
            rs[chk * CHUNK + f][l] = acc;
        }
        __syncthreads();  // before xs/ys reuse next chunk
    }

    // ---- phase 2: one thread per frame, fully-unrolled Levinson-Durbin + cepstrum ----
    if (tid < FPB && frame0 + tid < (long long)nframes) {
        float r[NR];
        #pragma unroll
        for (int i = 0; i < NR; ++i) r[i] = rs[tid][i];

        float a[MORD];
        #pragma unroll
        for (int i = 0; i < MORD; ++i) a[i] = 0.f;
        float E = r[0];
        #pragma unroll
        for (int i = 1; i <= MORD; ++i) {
            float acc = r[i];
            #pragma unroll
            for (int j = 0; j < i - 1; ++j) acc = fmaf(a[j], r[i - 1 - j], acc);
            float k = -acc / E;
            const int half = (i - 1) / 2;
            #pragma unroll
            for (int j = 0; j < half; ++j) {
                float t1 = a[j], t2 = a[i - 2 - j];
                a[j]         = fmaf(k, t2, t1);
                a[i - 2 - j] = fmaf(k, t1, t2);
            }
            if ((i - 1) & 1) {
                a[half] = fmaf(k, a[half], a[half]);  // middle element: a += k*a
            }
            a[i - 1] = k;
            E = E * (1.f - k * k);
        }

        // cepstrum: c[0]=log(K) is never used by recursion or output -> skipped
        float cc[NR];
        #pragma unroll
        for (int m = 1; m <= MORD; ++m) {
            float acc = a[m - 1];
            #pragma unroll
            for (int k2 = 1; k2 < m; ++k2)
                acc = fmaf(((float)k2 / (float)m) * cc[k2], a[m - k2 - 1], acc);
            cc[m] = -acc;
        }

        float o[16];
        #pragma unroll
        for (int m = 1; m <= MORD; ++m) o[m - 1] = cc[m] * lift_s[m];

        float4* op = reinterpret_cast<float4*>(out + (size_t)(frame0 + tid) * 16);
        op[0] = make_float4(o[0],  o[1],  o[2],  o[3]);
        op[1] = make_float4(o[4],  o[5],  o[6],  o[7]);
        op[2] = make_float4(o[8],  o[9],  o[10], o[11]);
        op[3] = make_float4(o[12], o[13], o[14], o[15]);
    }
}

extern "C" void kernel_launch(void* const* d_in, const int* in_sizes, int n_in,
                              void* d_out, int out_size, void* d_ws, size_t ws_size,
                              hipStream_t stream) {
    const float* x  = (const float*)d_in[0];
    float*      outp = (float*)d_out;
    int nframes = in_sizes[0] / NBINS;             // 131072 for (32,4096,257)
    int nblocks = (nframes + FPB - 1) / FPB;       // 2048
    plp_kernel<<<nblocks, 256, 0, stream>>>(x, outp, nframes);
}

// Round 2
// 221.294 us; speedup vs baseline: 1.0831x; 1.0831x over previous
//
#include <hip/hip_runtime.h>

#define NCH   40
#define MORD  16
#define NR    17
#define NY    42
#define NBINS 257

// ---------------- compile-time table generation (double precision) ----------------
namespace cfg {

constexpr double PI  = 3.14159265358979323846264338327950288;
constexpr double LN2 = 0.693147180559945309417232121458176568;

constexpr double cexp(double x) {           // |x| <= ~3.2
    double t = 1.0, s = 1.0;
    for (int i = 1; i < 40; ++i) { t *= x / i; s += t; }
    return s;
}

constexpr double clog(double z) {           // z > 0
    double lg = 0.0;
    while (z > 1.4142135623730951) { z *= 0.5; lg += LN2; }
    while (z < 0.7071067811865476) { z *= 2.0; lg -= LN2; }
    double u = (z - 1.0) / (z + 1.0), u2 = u * u, t = u, s = u;
    for (int k = 1; k < 24; ++k) { t *= u2; s += t / (2.0 * k + 1.0); }
    return lg + 2.0 * s;
}

constexpr double ccos(double x) {
    double tp = 2.0 * PI;
    double q = x / tp;
    long long k = (long long)(q + (q >= 0.0 ? 0.5 : -0.5));
    double r = x - (double)k * tp;          // r in [-pi, pi]
    double r2 = r * r, t = 1.0, s = 1.0;
    for (int i = 1; i < 20; ++i) { t *= -r2 / ((2.0 * i - 1.0) * (2.0 * i)); s += t; }
    return s;
}

constexpr double csin(double x) { return ccos(x - PI / 2.0); }

struct Tab {
    int   start[43];     // start[c] = first bin b with t_b > c, c = 0..41 (bins 1..255 used)
    float w[257];        // per-bin (t_b - c) for its group c
    float eql[NCH];
    float lift[NR];
    float ct[NR][NY];    // folded hfft cosine matrix, includes /82 and edge factors
    constexpr Tab() : start(), w(), eql(), lift(), ct() {
        const double lmax  = clog(87.0 / 7.0);   // ln(1 + 8000/700)
        const double U1127 = lmax / 41.0;        // U / 1127
        for (int c = 0; c <= 42 - 1; ++c) {
            double thr = 22.4 * (cexp((double)c * U1127) - 1.0);
            int s = (int)thr + 1;                // floor(+)+1
            if (s < 1) s = 1;
            if (s > 256) s = 256;
            start[c] = s;
        }
        start[42 - 1] = start[41];               // (index 41 is last used)
        for (int c = 0; c <= 40; ++c) {
            for (int b = start[c]; b < start[c + 1]; ++b) {
                double mel = 1127.0 * clog(1.0 + (double)b * 31.25 / 700.0);
                double t   = mel / (1127.0 * U1127);
                w[b] = (float)(t - (double)c);
            }
        }
        for (int c = 0; c < NCH; ++c) {
            double cf = 700.0 * (cexp((double)(c + 1) * U1127) - 1.0);
            double f2 = cf * cf;
            double e  = f2 / (f2 + 160000.0);
            e = e * e * (f2 + 1440000.0) / (f2 + 9610000.0);
            eql[c] = (float)e;
        }
        for (int m = 0; m < NR; ++m)
            lift[m] = (float)(1.0 + 11.0 * csin(PI * (double)m / 22.0));
        lift[0] = 2.0f;
        for (int l = 0; l < NR; ++l)
            for (int j = 0; j < NY; ++j) {
                double s = (j == 0 || j == NY - 1) ? 1.0 : 2.0;
                ct[l][j] = (float)(s * ccos(PI * (double)(j * l) / 41.0) / 82.0);
            }
    }
};

constexpr Tab T{};

} // namespace cfg

// ---------------- kernel: one thread per frame, all-register pipeline ----------------
__global__ __launch_bounds__(256) void plp_kernel(const float* __restrict__ x,
                                                  float* __restrict__ out,
                                                  int nframes)
{
    using cfg::T;
    const long long frame = (long long)blockIdx.x * blockDim.x + threadIdx.x;
    if (frame >= nframes) return;
    const float* __restrict__ xf = x + frame * NBINS;

    // ---- sparse mel filterbank: compile-time channel indices & literal weights ----
    float fb[NCH];
    #pragma unroll
    for (int c = 0; c < NCH; ++c) fb[c] = 0.f;

    #pragma unroll
    for (int c = 0; c <= 40; ++c) {
        #pragma unroll
        for (int b = T.start[c]; b < T.start[c + 1]; ++b) {
            float xv = xf[b];
            const float wa = T.w[b];             // t_b - c
            if (c < 40) fb[c]     = fmaf(wa, xv, fb[c]);          // ch==c side: t - c
            if (c >= 1) fb[c - 1] = fmaf(1.0f - wa, xv, fb[c - 1]); // ch-1 side: c+1 - t
        }
    }

    // ---- equal-loudness + cube-root compression (fast log/exp) ----
    float ys[NY];
    #pragma unroll
    for (int c = 0; c < NCH; ++c) {
        float v = fmaxf(fb[c], 1e-5f) * T.eql[c];
        ys[c + 1] = __expf(0.33f * __logf(v));
    }
    ys[0] = ys[1];
    ys[NY - 1] = ys[NY - 2];

    // ---- hfft-as-cosine-transform: 17 lags x 42 taps, literal coefficients ----
    float r[NR];
    #pragma unroll
    for (int l = 0; l < NR; ++l) {
        float acc = 0.f;
        #pragma unroll
        for (int j = 0; j < NY; ++j) acc = fmaf(T.ct[l][j], ys[j], acc);
        r[l] = acc;
    }

    // ---- Levinson-Durbin, fully unrolled in registers ----
    float a[MORD];
    #pragma unroll
    for (int i = 0; i < MORD; ++i) a[i] = 0.f;
    float E = r[0];
    #pragma unroll
    for (int i = 1; i <= MORD; ++i) {
        float acc = r[i];
        #pragma unroll
        for (int j = 0; j < i - 1; ++j) acc = fmaf(a[j], r[i - 1 - j], acc);
        float k = -acc / E;
        const int half = (i - 1) / 2;
        #pragma unroll
        for (int j = 0; j < half; ++j) {
            float t1 = a[j], t2 = a[i - 2 - j];
            a[j]         = fmaf(k, t2, t1);
            a[i - 2 - j] = fmaf(k, t1, t2);
        }
        if ((i - 1) & 1) a[half] = fmaf(k, a[half], a[half]);  // middle: a += k*a
        a[i - 1] = k;
        E = E * (1.f - k * k);
    }

    // ---- LPC -> cepstrum (c[0]=log K never used), lifter, store ----
    float cc[NR];
    #pragma unroll
    for (int m = 1; m <= MORD; ++m) {
        float acc = a[m - 1];
        #pragma unroll
        for (int k2 = 1; k2 < m; ++k2)
            acc = fmaf(((float)k2 / (float)m) * cc[k2], a[m - k2 - 1], acc);
        cc[m] = -acc;
    }

    float o[16];
    #pragma unroll
    for (int m = 1; m <= MORD; ++m) o[m - 1] = cc[m] * T.lift[m];

    float4* op = reinterpret_cast<float4*>(out + (size_t)frame * 16);
    op[0] = make_float4(o[0],  o[1],  o[2],  o[3]);
    op[1] = make_float4(o[4],  o[5],  o[6],  o[7]);
    op[2] = make_float4(o[8],  o[9],  o[10], o[11]);
    op[3] = make_float4(o[12], o[13], o[14], o[15]);
}

extern "C" void kernel_launch(void* const* d_in, const int* in_sizes, int n_in,
                              void* d_out, int out_size, void* d_ws, size_t ws_size,
                              hipStream_t stream) {
    const float* x   = (const float*)d_in[0];
    float*      outp = (float*)d_out;
    int nframes = in_sizes[0] / NBINS;                 // 131072 for (32,4096,257)
    int nblocks = (nframes + 255) / 256;               // 512
    plp_kernel<<<nblocks, 256, 0, stream>>>(x, outp, nframes);
}

// Round 3
// 204.562 us; speedup vs baseline: 1.1717x; 1.0818x over previous
//
#include <hip/hip_runtime.h>

#define NCH   40
#define MORD  16
#define NR    17
#define NY    42
#define NBINS 257
#define FPB   64   // frames per block == block size (one wave)

// ---------------- compile-time table generation (double precision) ----------------
namespace cfg {

constexpr double PI  = 3.14159265358979323846264338327950288;
constexpr double LN2 = 0.693147180559945309417232121458176568;

constexpr double cexp(double x) {           // |x| <= ~3.2
    double t = 1.0, s = 1.0;
    for (int i = 1; i < 40; ++i) { t *= x / i; s += t; }
    return s;
}

constexpr double clog(double z) {           // z > 0
    double lg = 0.0;
    while (z > 1.4142135623730951) { z *= 0.5; lg += LN2; }
    while (z < 0.7071067811865476) { z *= 2.0; lg -= LN2; }
    double u = (z - 1.0) / (z + 1.0), u2 = u * u, t = u, s = u;
    for (int k = 1; k < 24; ++k) { t *= u2; s += t / (2.0 * k + 1.0); }
    return lg + 2.0 * s;
}

constexpr double ccos(double x) {
    double tp = 2.0 * PI;
    double q = x / tp;
    long long k = (long long)(q + (q >= 0.0 ? 0.5 : -0.5));
    double r = x - (double)k * tp;          // r in [-pi, pi]
    double r2 = r * r, t = 1.0, s = 1.0;
    for (int i = 1; i < 20; ++i) { t *= -r2 / ((2.0 * i - 1.0) * (2.0 * i)); s += t; }
    return s;
}

constexpr double csin(double x) { return ccos(x - PI / 2.0); }

struct Tab {
    int   start[43];     // start[c] = first bin b with t_b > c, c = 0..41
    float w[257];        // per-bin (t_b - c) for its group c
    float eql[NCH];
    float lift[NR];
    float ct[NR][NY];    // folded hfft cosine matrix, includes /82 and edge factors
    constexpr Tab() : start(), w(), eql(), lift(), ct() {
        const double lmax  = clog(87.0 / 7.0);   // ln(1 + 8000/700)
        const double U1127 = lmax / 41.0;        // U / 1127
        for (int c = 0; c <= 41; ++c) {
            double thr = 22.4 * (cexp((double)c * U1127) - 1.0);
            int s = (int)thr + 1;                // floor(+)+1
            if (s < 1) s = 1;
            if (s > 256) s = 256;
            start[c] = s;
        }
        start[42 - 1] = start[41];
        for (int c = 0; c <= 40; ++c) {
            for (int b = start[c]; b < start[c + 1]; ++b) {
                double mel = 1127.0 * clog(1.0 + (double)b * 31.25 / 700.0);
                double t   = mel / (1127.0 * U1127);
                w[b] = (float)(t - (double)c);
            }
        }
        for (int c = 0; c < NCH; ++c) {
            double cf = 700.0 * (cexp((double)(c + 1) * U1127) - 1.0);
            double f2 = cf * cf;
            double e  = f2 / (f2 + 160000.0);
            e = e * e * (f2 + 1440000.0) / (f2 + 9610000.0);
            eql[c] = (float)e;
        }
        for (int m = 0; m < NR; ++m)
            lift[m] = (float)(1.0 + 11.0 * csin(PI * (double)m / 22.0));
        lift[0] = 2.0f;
        for (int l = 0; l < NR; ++l)
            for (int j = 0; j < NY; ++j) {
                double s = (j == 0 || j == NY - 1) ? 1.0 : 2.0;
                ct[l][j] = (float)(s * ccos(PI * (double)(j * l) / 41.0) / 82.0);
            }
    }
};

constexpr Tab T{};

} // namespace cfg

// -------- kernel: 1 wave stages a contiguous 64-frame slab to LDS, then
// -------- thread-per-frame all-register pipeline reading from LDS --------
__global__ __launch_bounds__(FPB) void plp_kernel(const float* __restrict__ x,
                                                  float* __restrict__ out,
                                                  int nframes)
{
    using cfg::T;
    __shared__ float slab[FPB * NBINS];          // 65792 B, exact linear copy
    const int tid = threadIdx.x;                 // 0..63, one wave
    const long long F0 = (long long)blockIdx.x * FPB;

    // ---- coalesced staging: 65 x global_load_lds(16B), 1 KB per call ----
    {
        const float* base = x + F0 * NBINS + tid * 4;   // lane's 16B piece of call 0
        const float* gend = x + (long long)nframes * NBINS;
        #pragma unroll
        for (int k = 0; k < 65; ++k) {
            // call 64 overlaps back so the 65792-B slab is covered exactly
            const int off = (k < 64) ? k * 256 : (FPB * NBINS - 256);   // floats
            const float* src = base + off;
            if (src + 4 > gend) src = gend - 4;          // safe clamp (never hit at 131072 frames)
            __builtin_amdgcn_global_load_lds(
                (const __attribute__((address_space(1))) void*)src,
                (__attribute__((address_space(3))) void*)(slab + off),
                16, 0, 0);
        }
    }
    __syncthreads();   // drains vmcnt -> slab valid

    const long long frame = F0 + tid;
    if (frame >= nframes) return;
    const float* __restrict__ fr = slab + tid * NBINS;   // bank (tid+b)%32 -> 2-way, free

    // ---- sparse mel filterbank: compile-time channel indices & literal weights ----
    float fb[NCH];
    #pragma unroll
    for (int c = 0; c < NCH; ++c) fb[c] = 0.f;

    #pragma unroll
    for (int c = 0; c <= 40; ++c) {
        #pragma unroll
        for (int b = T.start[c]; b < T.start[c + 1]; ++b) {
            float xv = fr[b];
            const float wa = T.w[b];             // t_b - c
            if (c < 40) fb[c]     = fmaf(wa, xv, fb[c]);            // ch==c side
            if (c >= 1) fb[c - 1] = fmaf(1.0f - wa, xv, fb[c - 1]); // ch-1 side
        }
    }

    // ---- equal-loudness + cube-root compression (fast log/exp) ----
    float ys[NY];
    #pragma unroll
    for (int c = 0; c < NCH; ++c) {
        float v = fmaxf(fb[c], 1e-5f) * T.eql[c];
        ys[c + 1] = __expf(0.33f * __logf(v));
    }
    ys[0] = ys[1];
    ys[NY - 1] = ys[NY - 2];

    // ---- hfft-as-cosine-transform: 17 lags x 42 taps, literal coefficients ----
    float r[NR];
    #pragma unroll
    for (int l = 0; l < NR; ++l) {
        float acc = 0.f;
        #pragma unroll
        for (int j = 0; j < NY; ++j) acc = fmaf(T.ct[l][j], ys[j], acc);
        r[l] = acc;
    }

    // ---- Levinson-Durbin, fully unrolled in registers ----
    float a[MORD];
    #pragma unroll
    for (int i = 0; i < MORD; ++i) a[i] = 0.f;
    float E = r[0];
    #pragma unroll
    for (int i = 1; i <= MORD; ++i) {
        float acc = r[i];
        #pragma unroll
        for (int j = 0; j < i - 1; ++j) acc = fmaf(a[j], r[i - 1 - j], acc);
        float k = -acc / E;
        const int half = (i - 1) / 2;
        #pragma unroll
        for (int j = 0; j < half; ++j) {
            float t1 = a[j], t2 = a[i - 2 - j];
            a[j]         = fmaf(k, t2, t1);
            a[i - 2 - j] = fmaf(k, t1, t2);
        }
        if ((i - 1) & 1) a[half] = fmaf(k, a[half], a[half]);  // middle: a += k*a
        a[i - 1] = k;
        E = E * (1.f - k * k);
    }

    // ---- LPC -> cepstrum (c[0]=log K never used), lifter, store ----
    float cc[NR];
    #pragma unroll
    for (int m = 1; m <= MORD; ++m) {
        float acc = a[m - 1];
        #pragma unroll
        for (int k2 = 1; k2 < m; ++k2)
            acc = fmaf(((float)k2 / (float)m) * cc[k2], a[m - k2 - 1], acc);
        cc[m] = -acc;
    }

    float o[16];
    #pragma unroll
    for (int m = 1; m <= MORD; ++m) o[m - 1] = cc[m] * T.lift[m];

    float4* op = reinterpret_cast<float4*>(out + (size_t)frame * 16);
    op[0] = make_float4(o[0],  o[1],  o[2],  o[3]);
    op[1] = make_float4(o[4],  o[5],  o[6],  o[7]);
    op[2] = make_float4(o[8],  o[9],  o[10], o[11]);
    op[3] = make_float4(o[12], o[13], o[14], o[15]);
}

extern "C" void kernel_launch(void* const* d_in, const int* in_sizes, int n_in,
                              void* d_out, int out_size, void* d_ws, size_t ws_size,
                              hipStream_t stream) {
    const float* x   = (const float*)d_in[0];
    float*      outp = (float*)d_out;
    int nframes = in_sizes[0] / NBINS;                 // 131072 for (32,4096,257)
    int nblocks = (nframes + FPB - 1) / FPB;           // 2048
    plp_kernel<<<nblocks, FPB, 0, stream>>>(x, outp, nframes);
}